// Round 1
// baseline (262.818 us; speedup 1.0000x reference)
//
#include <hip/hip_runtime.h>

// Problem constants
#define Bn   4
#define Cn   64
#define Hn   96
#define Wn   96
#define Gn   4
#define CGn  16      // Cn / Gn
#define Kn   3
#define KKn  9
#define NOFF 18      // 2*K*K offset channels
#define HWn  (Hn*Wn) // 9216

// ---------------------------------------------------------------------------
// Kernel 1: offset-predicting conv  (C=64 -> 18, 3x3, pad 1)
// One thread per output element. Block of 256 covers a contiguous slice of one
// (b, o) plane (HW=9216 % 256 == 0), so the 576 weights for channel o are
// block-uniform -> staged in LDS.
// ---------------------------------------------------------------------------
__global__ __launch_bounds__(256) void offset_conv_kernel(
    const float* __restrict__ x, const float* __restrict__ w,
    const float* __restrict__ bias, float* __restrict__ out)
{
    __shared__ float wsm[Cn * KKn];       // 576 floats, this block's out-channel o
    const int base = blockIdx.x * 256;
    const int o = (base / HWn) % NOFF;
    const int b = base / (NOFF * HWn);

    for (int i = threadIdx.x; i < Cn * KKn; i += 256)
        wsm[i] = w[o * Cn * KKn + i];
    __syncthreads();

    const int pos = (base % HWn) + threadIdx.x;
    const int ho = pos / Wn, wo = pos % Wn;

    float acc = bias[o];
    const float* xb = x + b * Cn * HWn;

    for (int ci = 0; ci < Cn; ci++) {
        const float* xc = xb + ci * HWn;
        const float* wc = wsm + ci * KKn;
        #pragma unroll
        for (int ki = 0; ki < 3; ki++) {
            const int y = ho - 1 + ki;
            if (y < 0 || y >= Hn) continue;
            const float* xr = xc + y * Wn;
            #pragma unroll
            for (int kj = 0; kj < 3; kj++) {
                const int xx = wo - 1 + kj;
                if (xx < 0 || xx >= Wn) continue;
                acc += xr[xx] * wc[ki * 3 + kj];
            }
        }
    }
    out[(b * NOFF + o) * HWn + pos] = acc;
}

// ---------------------------------------------------------------------------
// Kernel 2: deformable conv. One thread per (b, g, ho, wo) computes the 16
// output channels of group g: each bilinear sample is reused by 16 outputs.
// Group weights (16*16*9 = 2304 floats) staged in LDS; inner-d reads are
// wave-uniform broadcasts.
// ---------------------------------------------------------------------------
__global__ __launch_bounds__(256) void deform_kernel(
    const float* __restrict__ x, const float* __restrict__ off,
    const float* __restrict__ wdef, float* __restrict__ out)
{
    __shared__ float wsm[CGn * CGn * KKn];     // [d][c][k] for this group
    const int base = blockIdx.x * 256;
    const int g = (base / HWn) % Gn;
    const int b = base / (Gn * HWn);

    for (int i = threadIdx.x; i < CGn * CGn * KKn; i += 256)
        wsm[i] = wdef[g * CGn * CGn * KKn + i];
    __syncthreads();

    const int pos = (base % HWn) + threadIdx.x;
    const int ho = pos / Wn, wo = pos % Wn;

    float acc[CGn];
    #pragma unroll
    for (int d = 0; d < CGn; d++) acc[d] = 0.f;

    const float* xb   = x   + (b * Cn + g * CGn) * HWn;
    const float* offb = off + b * NOFF * HWn + pos;

    for (int k = 0; k < KKn; k++) {
        const int ki = k / 3, kj = k % 3;
        const float dy = offb[(2 * k)     * HWn];
        const float dx = offb[(2 * k + 1) * HWn];
        const float ysf = (float)(ho - 1 + ki) + dy;
        const float xsf = (float)(wo - 1 + kj) + dx;
        const float y0f = floorf(ysf), x0f = floorf(xsf);
        const int   y0  = (int)y0f,    x0  = (int)x0f;
        const float wy1 = ysf - y0f, wx1 = xsf - x0f;
        const float wy0 = 1.f - wy1, wx0 = 1.f - wx1;

        const bool vy0 = (y0 >= 0)  && (y0 < Hn);
        const bool vy1 = (y0 >= -1) && (y0 < Hn - 1);
        const bool vx0 = (x0 >= 0)  && (x0 < Wn);
        const bool vx1 = (x0 >= -1) && (x0 < Wn - 1);

        const int cy0 = min(max(y0,     0), Hn - 1);
        const int cy1 = min(max(y0 + 1, 0), Hn - 1);
        const int cx0 = min(max(x0,     0), Wn - 1);
        const int cx1 = min(max(x0 + 1, 0), Wn - 1);

        const float w00 = wy0 * wx0 * ((vy0 && vx0) ? 1.f : 0.f);
        const float w01 = wy0 * wx1 * ((vy0 && vx1) ? 1.f : 0.f);
        const float w10 = wy1 * wx0 * ((vy1 && vx0) ? 1.f : 0.f);
        const float w11 = wy1 * wx1 * ((vy1 && vx1) ? 1.f : 0.f);

        const int i00 = cy0 * Wn + cx0, i01 = cy0 * Wn + cx1;
        const int i10 = cy1 * Wn + cx0, i11 = cy1 * Wn + cx1;

        for (int c = 0; c < CGn; c++) {
            const float* xc = xb + c * HWn;
            const float s = w00 * xc[i00] + w01 * xc[i01]
                          + w10 * xc[i10] + w11 * xc[i11];
            const float* wp = wsm + c * KKn + k;
            #pragma unroll
            for (int d = 0; d < CGn; d++)
                acc[d] += s * wp[d * CGn * KKn];
        }
    }

    float* ob = out + (b * Cn + g * CGn) * HWn + pos;
    #pragma unroll
    for (int d = 0; d < CGn; d++) ob[d * HWn] = acc[d];
}

// ---------------------------------------------------------------------------
extern "C" void kernel_launch(void* const* d_in, const int* in_sizes, int n_in,
                              void* d_out, int out_size, void* d_ws, size_t ws_size,
                              hipStream_t stream) {
    const float* x     = (const float*)d_in[0];
    const float* w_off = (const float*)d_in[1];
    const float* b_off = (const float*)d_in[2];
    const float* w_def = (const float*)d_in[3];
    float* out = (float*)d_out;
    float* offset = (float*)d_ws;   // B*18*H*W floats = 2.65 MB scratch

    const int total_off = Bn * NOFF * HWn;   // 663552
    const int total_def = Bn * Gn * HWn;     // 147456

    offset_conv_kernel<<<total_off / 256, 256, 0, stream>>>(x, w_off, b_off, offset);
    deform_kernel<<<total_def / 256, 256, 0, stream>>>(x, offset, w_def, out);
}

// Round 2
// 254.017 us; speedup vs baseline: 1.0346x; 1.0346x over previous
//
#include <hip/hip_runtime.h>

// Problem constants
#define Bn   4
#define Cn   64
#define Hn   96
#define Wn   96
#define Gn   4
#define CGn  16      // Cn / Gn
#define KKn  9
#define NOFF 18      // 2*K*K offset channels
#define HWn  (Hn*Wn) // 9216

// ws layout (floats)
#define OFF_BASE  0                       // B*18*HW = 663552 offsets
#define WT_BASE   (Bn*NOFF*HWn)           // 663552: wT[ci][o][k]  (64*18*9 = 10368)
#define WDT_BASE  (WT_BASE + Cn*NOFF*KKn) // wdT[g][c][k][d] (4*16*9*16 = 9216)

// ---------------------------------------------------------------------------
// Kernel 0: weight reordering into ws.
//   wT [ci][o][k] = w_off[o][ci][k]          -> per-ci contiguous 162 floats
//   wdT[g][c][k][d] = w_def[g*16+d][c][k]    -> per-(c,k) contiguous 16 floats
// ---------------------------------------------------------------------------
__global__ __launch_bounds__(256) void prep_kernel(
    const float* __restrict__ w_off, const float* __restrict__ w_def,
    float* __restrict__ ws)
{
    const int i = blockIdx.x * 256 + threadIdx.x;
    const int NT = Cn * NOFF * KKn;        // 10368
    const int ND = Gn * CGn * KKn * CGn;   // 9216
    if (i < NT) {
        const int ci = i / (NOFF * KKn);
        const int r  = i % (NOFF * KKn);
        const int o  = r / KKn, k = r % KKn;
        ws[WT_BASE + i] = w_off[(o * Cn + ci) * KKn + k];
    } else if (i < NT + ND) {
        const int j = i - NT;
        const int d = j % CGn;
        const int t = j / CGn;
        const int k = t % KKn;
        const int u = t / KKn;
        const int c = u % CGn, g = u / CGn;
        ws[WDT_BASE + j] = w_def[((g * CGn + d) * CGn + c) * KKn + k];
    }
}

// ---------------------------------------------------------------------------
// Kernel 1: offset conv (64 -> 18, 3x3, pad 1).
// Thread per (b, pos), computes ALL 18 output channels.
// Weights read with block-uniform addresses from wT -> scalar (s_load) pipe.
// ---------------------------------------------------------------------------
__global__ __launch_bounds__(256) void offset_conv_v2(
    const float* __restrict__ x, const float* __restrict__ ws,
    const float* __restrict__ bias, float* __restrict__ offs)
{
    const float* __restrict__ wT = ws + WT_BASE;

    const int base = blockIdx.x * 256;          // grid = B*HW/256 = 144
    const int b = base / HWn;
    const int pos = (base % HWn) + threadIdx.x;
    const int ho = pos / Wn, wo = pos % Wn;

    float acc[NOFF];
    #pragma unroll
    for (int o = 0; o < NOFF; o++) acc[o] = bias[o];

    const float* xb = x + b * Cn * HWn;

    for (int ci = 0; ci < Cn; ci++) {
        const float* xc = xb + ci * HWn;
        float xv[KKn];
        #pragma unroll
        for (int ki = 0; ki < 3; ki++) {
            const int y = ho - 1 + ki;
            const bool vy = (y >= 0) && (y < Hn);
            const float* xr = xc + y * Wn;
            #pragma unroll
            for (int kj = 0; kj < 3; kj++) {
                const int xx = wo - 1 + kj;
                const bool v = vy && (xx >= 0) && (xx < Wn);
                xv[ki * 3 + kj] = v ? xr[xx] : 0.f;
            }
        }
        const float* wp = wT + ci * (NOFF * KKn);   // uniform address
        #pragma unroll
        for (int o = 0; o < NOFF; o++) {
            #pragma unroll
            for (int k = 0; k < KKn; k++)
                acc[o] += xv[k] * wp[o * KKn + k];
        }
    }

    float* ob = offs + b * NOFF * HWn + pos;
    #pragma unroll
    for (int o = 0; o < NOFF; o++) ob[o * HWn] = acc[o];
}

// ---------------------------------------------------------------------------
// Kernel 2: deformable conv. Thread per (b, g, pos) -> 16 output channels.
// Phase 1: all 9 taps' corner indices + bilinear weights in registers.
// Phase 2: per input channel, 36 gathers issued together, then 180 FMAs
// against scalar-loaded (uniform) weights.
// ---------------------------------------------------------------------------
__global__ __launch_bounds__(256) void deform_v2(
    const float* __restrict__ x, const float* __restrict__ ws,
    float* __restrict__ out)
{
    const float* __restrict__ offp = ws + OFF_BASE;
    const float* __restrict__ wdT  = ws + WDT_BASE;

    const int base = blockIdx.x * 256;          // grid = B*G*HW/256 = 576
    const int g = (base / HWn) % Gn;
    const int b = base / (Gn * HWn);
    const int pos = (base % HWn) + threadIdx.x;
    const int ho = pos / Wn, wo = pos % Wn;

    const float* ob = offp + b * NOFF * HWn + pos;

    int   cidx[KKn][4];
    float cwt [KKn][4];

    #pragma unroll
    for (int k = 0; k < KKn; k++) {
        const int ki = k / 3, kj = k % 3;
        const float dy = ob[(2 * k)     * HWn];
        const float dx = ob[(2 * k + 1) * HWn];
        const float ysf = (float)(ho - 1 + ki) + dy;
        const float xsf = (float)(wo - 1 + kj) + dx;
        const float y0f = floorf(ysf), x0f = floorf(xsf);
        const int   y0  = (int)y0f,    x0  = (int)x0f;
        const float wy1 = ysf - y0f, wx1 = xsf - x0f;
        const float wy0 = 1.f - wy1, wx0 = 1.f - wx1;

        const bool vy0 = (y0 >= 0)  && (y0 < Hn);
        const bool vy1 = (y0 >= -1) && (y0 < Hn - 1);
        const bool vx0 = (x0 >= 0)  && (x0 < Wn);
        const bool vx1 = (x0 >= -1) && (x0 < Wn - 1);

        const int cy0 = min(max(y0,     0), Hn - 1);
        const int cy1 = min(max(y0 + 1, 0), Hn - 1);
        const int cx0 = min(max(x0,     0), Wn - 1);
        const int cx1 = min(max(x0 + 1, 0), Wn - 1);

        cwt[k][0] = wy0 * wx0 * ((vy0 && vx0) ? 1.f : 0.f);
        cwt[k][1] = wy0 * wx1 * ((vy0 && vx1) ? 1.f : 0.f);
        cwt[k][2] = wy1 * wx0 * ((vy1 && vx0) ? 1.f : 0.f);
        cwt[k][3] = wy1 * wx1 * ((vy1 && vx1) ? 1.f : 0.f);

        cidx[k][0] = cy0 * Wn + cx0;
        cidx[k][1] = cy0 * Wn + cx1;
        cidx[k][2] = cy1 * Wn + cx0;
        cidx[k][3] = cy1 * Wn + cx1;
    }

    const float* xb = x + (b * Cn + g * CGn) * HWn;
    const float* wg = wdT + g * (CGn * KKn * CGn);   // uniform

    float acc[CGn];
    #pragma unroll
    for (int d = 0; d < CGn; d++) acc[d] = 0.f;

    for (int c = 0; c < CGn; c++) {
        const float* xc = xb + c * HWn;
        // issue all 36 gathers
        float v[KKn][4];
        #pragma unroll
        for (int k = 0; k < KKn; k++) {
            #pragma unroll
            for (int j = 0; j < 4; j++)
                v[k][j] = xc[cidx[k][j]];
        }
        // bilinear combine
        float s[KKn];
        #pragma unroll
        for (int k = 0; k < KKn; k++)
            s[k] = cwt[k][0] * v[k][0] + cwt[k][1] * v[k][1]
                 + cwt[k][2] * v[k][2] + cwt[k][3] * v[k][3];
        // contraction: weights uniform -> scalar loads
        const float* wc = wg + c * (KKn * CGn);
        #pragma unroll
        for (int k = 0; k < KKn; k++) {
            #pragma unroll
            for (int d = 0; d < CGn; d++)
                acc[d] += s[k] * wc[k * CGn + d];
        }
    }

    float* op = out + (b * Cn + g * CGn) * HWn + pos;
    #pragma unroll
    for (int d = 0; d < CGn; d++) op[d * HWn] = acc[d];
}

// ---------------------------------------------------------------------------
extern "C" void kernel_launch(void* const* d_in, const int* in_sizes, int n_in,
                              void* d_out, int out_size, void* d_ws, size_t ws_size,
                              hipStream_t stream) {
    const float* x     = (const float*)d_in[0];
    const float* w_off = (const float*)d_in[1];
    const float* b_off = (const float*)d_in[2];
    const float* w_def = (const float*)d_in[3];
    float* out = (float*)d_out;
    float* ws  = (float*)d_ws;

    const int n_prep = Cn * NOFF * KKn + Gn * CGn * KKn * CGn;  // 19584
    prep_kernel<<<(n_prep + 255) / 256, 256, 0, stream>>>(w_off, w_def, ws);

    offset_conv_v2<<<Bn * HWn / 256, 256, 0, stream>>>(x, ws, b_off, ws + OFF_BASE);

    deform_v2<<<Bn * Gn * HWn / 256, 256, 0, stream>>>(x, ws, out);
}

// Round 3
// 123.731 us; speedup vs baseline: 2.1241x; 2.0530x over previous
//
#include <hip/hip_runtime.h>

// Problem constants
#define Bn   4
#define Cn   64
#define Hn   96
#define Wn   96
#define Gn   4
#define CGn  16      // Cn / Gn
#define KKn  9
#define NOFF 18      // 2*K*K offset channels
#define HWn  (Hn*Wn) // 9216

// ws layout (floats)
#define OFF_BASE  0                       // B*18*HW = 663552 offsets
#define WT_BASE   (Bn*NOFF*HWn)           // wT[ci][o][k]  (64*18*9 = 10368)
#define WDT_BASE  (WT_BASE + Cn*NOFF*KKn) // wdT[g][c][k][d] (4*16*9*16 = 9216)

// ---------------------------------------------------------------------------
// Kernel 0: weight reordering into ws.
// ---------------------------------------------------------------------------
__global__ __launch_bounds__(256) void prep_kernel(
    const float* __restrict__ w_off, const float* __restrict__ w_def,
    float* __restrict__ ws)
{
    const int i = blockIdx.x * 256 + threadIdx.x;
    const int NT = Cn * NOFF * KKn;        // 10368
    const int ND = Gn * CGn * KKn * CGn;   // 9216
    if (i < NT) {
        const int ci = i / (NOFF * KKn);
        const int r  = i % (NOFF * KKn);
        const int o  = r / KKn, k = r % KKn;
        ws[WT_BASE + i] = w_off[(o * Cn + ci) * KKn + k];
    } else if (i < NT + ND) {
        const int j = i - NT;
        const int d = j % CGn;
        const int t = j / CGn;
        const int k = t % KKn;
        const int u = t / KKn;
        const int c = u % CGn, g = u / CGn;
        ws[WDT_BASE + j] = w_def[((g * CGn + d) * CGn + c) * KKn + k];
    }
}

// ---------------------------------------------------------------------------
// Kernel 1: offset conv (64 -> 18, 3x3, pad 1), ci-split across 8 waves.
// Block 512 = 8 waves; wave w handles ci in [8w, 8w+8) for 64 positions.
// Partials reduced via LDS. Weight reads wave-uniform -> scalar pipe.
// ---------------------------------------------------------------------------
#define OCB 64                              // positions per block
__global__ __launch_bounds__(512) void offset_conv_v3(
    const float* __restrict__ x, const float* __restrict__ ws,
    const float* __restrict__ bias, float* __restrict__ offs)
{
    __shared__ float red[8][OCB][NOFF + 1];  // 38912 B
    const float* __restrict__ wT = ws + WT_BASE;

    const int wave = threadIdx.x >> 6;       // ci chunk 0..7
    const int lane = threadIdx.x & 63;       // pos within block
    const int nb   = HWn / OCB;              // 144
    const int b    = blockIdx.x / nb;
    const int pbase= (blockIdx.x % nb) * OCB;
    const int pos  = pbase + lane;
    const int ho = pos / Wn, wo = pos % Wn;

    float acc[NOFF];
    #pragma unroll
    for (int o = 0; o < NOFF; o++) acc[o] = 0.f;

    const float* xb = x + b * Cn * HWn;
    const int ci0 = __builtin_amdgcn_readfirstlane(wave * 8);

    for (int ci = ci0; ci < ci0 + 8; ci++) {
        const float* xc = xb + ci * HWn;
        float xv[KKn];
        #pragma unroll
        for (int ki = 0; ki < 3; ki++) {
            const int y = ho - 1 + ki;
            const bool vy = (y >= 0) && (y < Hn);
            const float* xr = xc + y * Wn;
            #pragma unroll
            for (int kj = 0; kj < 3; kj++) {
                const int xx = wo - 1 + kj;
                const bool v = vy && (xx >= 0) && (xx < Wn);
                xv[ki * 3 + kj] = v ? xr[xx] : 0.f;
            }
        }
        const float* wp = wT + ci * (NOFF * KKn);   // wave-uniform address
        #pragma unroll
        for (int o = 0; o < NOFF; o++) {
            #pragma unroll
            for (int k = 0; k < KKn; k++)
                acc[o] += xv[k] * wp[o * KKn + k];
        }
    }

    #pragma unroll
    for (int o = 0; o < NOFF; o++) red[wave][lane][o] = acc[o];
    __syncthreads();

    // reduce 8 partials; 18*64 = 1152 outputs, 512 threads
    for (int idx = threadIdx.x; idx < NOFF * OCB; idx += 512) {
        const int o = idx / OCB;
        const int p = idx % OCB;
        float s = bias[o];
        #pragma unroll
        for (int w2 = 0; w2 < 8; w2++) s += red[w2][p][o];
        offs[(b * NOFF + o) * HWn + pbase + p] = s;
    }
}

// ---------------------------------------------------------------------------
// Kernel 2: deformable conv, c-split by 2.
// Block 256 = 128 positions x 2 chunks (8 input channels each).
// Each thread computes 16 output-channel partials; chunk-1 partials
// reduced into chunk-0 via LDS.
// ---------------------------------------------------------------------------
__global__ __launch_bounds__(256) void deform_v3(
    const float* __restrict__ x, const float* __restrict__ ws,
    float* __restrict__ out)
{
    __shared__ float red[128][CGn + 1];   // 8704 B
    const float* __restrict__ offp = ws + OFF_BASE;
    const float* __restrict__ wdT  = ws + WDT_BASE;

    const int nb = HWn / 128;             // 72
    const int bg = blockIdx.x / nb;       // 0..15
    const int g  = bg & (Gn - 1);
    const int b  = bg >> 2;
    const int chunk = threadIdx.x >> 7;   // 0 or 1
    const int pl    = threadIdx.x & 127;
    const int pos   = (blockIdx.x % nb) * 128 + pl;
    const int ho = pos / Wn, wo = pos % Wn;

    const float* ob = offp + b * NOFF * HWn + pos;

    int   cidx[KKn][4];
    float cwt [KKn][4];

    #pragma unroll
    for (int k = 0; k < KKn; k++) {
        const int ki = k / 3, kj = k % 3;
        const float dy = ob[(2 * k)     * HWn];
        const float dx = ob[(2 * k + 1) * HWn];
        const float ysf = (float)(ho - 1 + ki) + dy;
        const float xsf = (float)(wo - 1 + kj) + dx;
        const float y0f = floorf(ysf), x0f = floorf(xsf);
        const int   y0  = (int)y0f,    x0  = (int)x0f;
        const float wy1 = ysf - y0f, wx1 = xsf - x0f;
        const float wy0 = 1.f - wy1, wx0 = 1.f - wx1;

        const bool vy0 = (y0 >= 0)  && (y0 < Hn);
        const bool vy1 = (y0 >= -1) && (y0 < Hn - 1);
        const bool vx0 = (x0 >= 0)  && (x0 < Wn);
        const bool vx1 = (x0 >= -1) && (x0 < Wn - 1);

        const int cy0 = min(max(y0,     0), Hn - 1);
        const int cy1 = min(max(y0 + 1, 0), Hn - 1);
        const int cx0 = min(max(x0,     0), Wn - 1);
        const int cx1 = min(max(x0 + 1, 0), Wn - 1);

        cwt[k][0] = wy0 * wx0 * ((vy0 && vx0) ? 1.f : 0.f);
        cwt[k][1] = wy0 * wx1 * ((vy0 && vx1) ? 1.f : 0.f);
        cwt[k][2] = wy1 * wx0 * ((vy1 && vx0) ? 1.f : 0.f);
        cwt[k][3] = wy1 * wx1 * ((vy1 && vx1) ? 1.f : 0.f);

        cidx[k][0] = cy0 * Wn + cx0;
        cidx[k][1] = cy0 * Wn + cx1;
        cidx[k][2] = cy1 * Wn + cx0;
        cidx[k][3] = cy1 * Wn + cx1;
    }

    const int c0 = __builtin_amdgcn_readfirstlane(chunk * 8);
    const float* xb = x + (b * Cn + g * CGn) * HWn;
    const float* wg = wdT + g * (CGn * KKn * CGn);   // wave-uniform base

    float acc[CGn];
    #pragma unroll
    for (int d = 0; d < CGn; d++) acc[d] = 0.f;

    for (int c = c0; c < c0 + 8; c++) {
        const float* xc = xb + c * HWn;
        const float* wc = wg + c * (KKn * CGn);
        #pragma unroll
        for (int k = 0; k < KKn; k++) {
            const float v0 = xc[cidx[k][0]];
            const float v1 = xc[cidx[k][1]];
            const float v2 = xc[cidx[k][2]];
            const float v3 = xc[cidx[k][3]];
            const float s = cwt[k][0] * v0 + cwt[k][1] * v1
                          + cwt[k][2] * v2 + cwt[k][3] * v3;
            #pragma unroll
            for (int d = 0; d < CGn; d++)
                acc[d] += s * wc[k * CGn + d];
        }
    }

    if (chunk == 1) {
        #pragma unroll
        for (int d = 0; d < CGn; d++) red[pl][d] = acc[d];
    }
    __syncthreads();
    if (chunk == 0) {
        float* op = out + (b * Cn + g * CGn) * HWn + pos;
        #pragma unroll
        for (int d = 0; d < CGn; d++) op[d * HWn] = acc[d] + red[pl][d];
    }
}

// ---------------------------------------------------------------------------
extern "C" void kernel_launch(void* const* d_in, const int* in_sizes, int n_in,
                              void* d_out, int out_size, void* d_ws, size_t ws_size,
                              hipStream_t stream) {
    const float* x     = (const float*)d_in[0];
    const float* w_off = (const float*)d_in[1];
    const float* b_off = (const float*)d_in[2];
    const float* w_def = (const float*)d_in[3];
    float* out = (float*)d_out;
    float* ws  = (float*)d_ws;

    const int n_prep = Cn * NOFF * KKn + Gn * CGn * KKn * CGn;  // 19584
    prep_kernel<<<(n_prep + 255) / 256, 256, 0, stream>>>(w_off, w_def, ws);

    offset_conv_v3<<<Bn * (HWn / OCB), 512, 0, stream>>>(x, ws, b_off, ws + OFF_BASE);

    deform_v3<<<Bn * Gn * (HWn / 128), 256, 0, stream>>>(x, ws, out);
}

// Round 4
// 102.231 us; speedup vs baseline: 2.5708x; 1.2103x over previous
//
#include <hip/hip_runtime.h>

// Problem constants
#define Bn   4
#define Cn   64
#define Hn   96
#define Wn   96
#define Gn   4
#define CGn  16      // Cn / Gn
#define KKn  9
#define NOFF 18      // 2*K*K offset channels
#define HWn  (Hn*Wn) // 9216

// ws layout (floats)
#define OFF_BASE  0                            // B*HW*18 pos-major offsets (663552)
#define WT_BASE   (Bn*HWn*NOFF)                // wT[ci][o][k]  (10368)
#define WDT_BASE  (WT_BASE + Cn*NOFF*KKn)      // wd2[g][k][c][d] (9216)
#define XT_BASE   (WDT_BASE + Gn*KKn*CGn*CGn)  // xT[b][pos][c] NHWC (2359296)
// total = 3042432 floats = 12.2 MB

// ---------------------------------------------------------------------------
// Kernel 0: weight reordering.
//   wT [ci][o][k]   = w_off[o][ci][k]
//   wd2[g][k][c][d] = w_def[g*16+d][c][k]
// ---------------------------------------------------------------------------
__global__ __launch_bounds__(256) void prep_kernel(
    const float* __restrict__ w_off, const float* __restrict__ w_def,
    float* __restrict__ ws)
{
    const int i = blockIdx.x * 256 + threadIdx.x;
    const int NT = Cn * NOFF * KKn;        // 10368
    const int ND = Gn * KKn * CGn * CGn;   // 9216
    if (i < NT) {
        const int ci = i / (NOFF * KKn);
        const int r  = i % (NOFF * KKn);
        const int o  = r / KKn, k = r % KKn;
        ws[WT_BASE + i] = w_off[(o * Cn + ci) * KKn + k];
    } else if (i < NT + ND) {
        const int j = i - NT;
        const int d = j % CGn;
        const int c = (j / CGn) % CGn;
        const int k = (j / (CGn * CGn)) % KKn;
        const int g = j / (KKn * CGn * CGn);
        ws[WDT_BASE + j] = w_def[((g * CGn + d) * CGn + c) * KKn + k];
    }
}

// ---------------------------------------------------------------------------
// Kernel 0b: x NCHW -> NHWC (xT[b][pos][c]) via LDS tile transpose.
// ---------------------------------------------------------------------------
__global__ __launch_bounds__(256) void transpose_x(
    const float* __restrict__ x, float* __restrict__ xT)
{
    __shared__ float t[64][65];
    const int nb = HWn / 64;               // 144
    const int b  = blockIdx.x / nb;
    const int p0 = (blockIdx.x % nb) * 64;

    for (int i = threadIdx.x; i < 64 * 64; i += 256) {
        const int c = i >> 6, l = i & 63;
        t[c][l] = x[(b * Cn + c) * HWn + p0 + l];
    }
    __syncthreads();
    for (int i = threadIdx.x; i < 64 * 64; i += 256) {
        const int l = i >> 6, c = i & 63;
        xT[(b * HWn + p0 + l) * Cn + c] = t[c][l];
    }
}

// ---------------------------------------------------------------------------
// Kernel 1: offset conv (64 -> 18, 3x3, pad 1), ci-split across 8 waves.
// Writes offsets POS-MAJOR: offs[(b*HW+pos)*18 + o].
// ---------------------------------------------------------------------------
#define OCB 64
__global__ __launch_bounds__(512) void offset_conv_v3(
    const float* __restrict__ x, const float* __restrict__ ws,
    const float* __restrict__ bias, float* __restrict__ offs)
{
    __shared__ float red[8][OCB][NOFF + 1];
    const float* __restrict__ wT = ws + WT_BASE;

    const int wave = threadIdx.x >> 6;
    const int lane = threadIdx.x & 63;
    const int nb   = HWn / OCB;            // 144
    const int b    = blockIdx.x / nb;
    const int pbase= (blockIdx.x % nb) * OCB;
    const int pos  = pbase + lane;
    const int ho = pos / Wn, wo = pos % Wn;

    float acc[NOFF];
    #pragma unroll
    for (int o = 0; o < NOFF; o++) acc[o] = 0.f;

    const float* xb = x + b * Cn * HWn;
    const int ci0 = __builtin_amdgcn_readfirstlane(wave * 8);

    for (int ci = ci0; ci < ci0 + 8; ci++) {
        const float* xc = xb + ci * HWn;
        float xv[KKn];
        #pragma unroll
        for (int ki = 0; ki < 3; ki++) {
            const int y = ho - 1 + ki;
            const bool vy = (y >= 0) && (y < Hn);
            const float* xr = xc + y * Wn;
            #pragma unroll
            for (int kj = 0; kj < 3; kj++) {
                const int xx = wo - 1 + kj;
                const bool v = vy && (xx >= 0) && (xx < Wn);
                xv[ki * 3 + kj] = v ? xr[xx] : 0.f;
            }
        }
        const float* wp = wT + ci * (NOFF * KKn);   // wave-uniform
        #pragma unroll
        for (int o = 0; o < NOFF; o++) {
            #pragma unroll
            for (int k = 0; k < KKn; k++)
                acc[o] += xv[k] * wp[o * KKn + k];
        }
    }

    #pragma unroll
    for (int o = 0; o < NOFF; o++) red[wave][lane][o] = acc[o];
    __syncthreads();

    // 1152 outputs; o fastest -> pos-major coalesced stores
    for (int idx = threadIdx.x; idx < NOFF * OCB; idx += 512) {
        const int o = idx % NOFF;
        const int p = idx / NOFF;
        float s = bias[o];
        #pragma unroll
        for (int w2 = 0; w2 < 8; w2++) s += red[w2][p][o];
        offs[(b * HWn + pbase + p) * NOFF + o] = s;
    }
}

// ---------------------------------------------------------------------------
// Kernel 2: deformable conv from NHWC x. Block 256 = 128 pos x 2 c-chunks.
// Per tap: float2 offset read, 8 float4 gathers (16 channels' 4 corners),
// bilinear combine, 128 FMAs vs scalar-loaded weights.
// ---------------------------------------------------------------------------
__global__ __launch_bounds__(256) void deform_v4(
    const float* __restrict__ ws, float* __restrict__ out)
{
    __shared__ float red[128][CGn + 1];
    const float* __restrict__ off2 = ws + OFF_BASE;
    const float* __restrict__ wd   = ws + WDT_BASE;
    const float* __restrict__ xT   = ws + XT_BASE;

    const int nb = HWn / 128;              // 72
    const int bg = blockIdx.x / nb;
    const int g  = bg & (Gn - 1);
    const int b  = bg >> 2;
    const int chunk = threadIdx.x >> 7;    // wave-uniform (0 or 1)
    const int pl    = threadIdx.x & 127;
    const int pos   = (blockIdx.x % nb) * 128 + pl;
    const int ho = pos / Wn, wo = pos % Wn;

    const float2* op2 = (const float2*)(off2 + (b * HWn + pos) * NOFF);

    const int c0 = __builtin_amdgcn_readfirstlane(chunk * 8);
    const float* xch = xT + (b * HWn) * Cn + g * CGn + c0;  // channel base
    const float* wg  = wd + g * (KKn * CGn * CGn) + c0 * CGn;

    float acc[CGn];
    #pragma unroll
    for (int d = 0; d < CGn; d++) acc[d] = 0.f;

    #pragma unroll
    for (int k = 0; k < KKn; k++) {
        const int ki = k / 3, kj = k % 3;
        const float2 dyx = op2[k];
        const float ysf = (float)(ho - 1 + ki) + dyx.x;
        const float xsf = (float)(wo - 1 + kj) + dyx.y;
        const float y0f = floorf(ysf), x0f = floorf(xsf);
        const int   y0  = (int)y0f,    x0  = (int)x0f;
        const float wy1 = ysf - y0f, wx1 = xsf - x0f;
        const float wy0 = 1.f - wy1, wx0 = 1.f - wx1;

        const bool vy0 = (y0 >= 0)  && (y0 < Hn);
        const bool vy1 = (y0 >= -1) && (y0 < Hn - 1);
        const bool vx0 = (x0 >= 0)  && (x0 < Wn);
        const bool vx1 = (x0 >= -1) && (x0 < Wn - 1);

        const int cy0 = min(max(y0,     0), Hn - 1);
        const int cy1 = min(max(y0 + 1, 0), Hn - 1);
        const int cx0 = min(max(x0,     0), Wn - 1);
        const int cx1 = min(max(x0 + 1, 0), Wn - 1);

        const float w00 = wy0 * wx0 * ((vy0 && vx0) ? 1.f : 0.f);
        const float w01 = wy0 * wx1 * ((vy0 && vx1) ? 1.f : 0.f);
        const float w10 = wy1 * wx0 * ((vy1 && vx0) ? 1.f : 0.f);
        const float w11 = wy1 * wx1 * ((vy1 && vx1) ? 1.f : 0.f);

        const float* p00 = xch + (cy0 * Wn + cx0) * Cn;
        const float* p01 = xch + (cy0 * Wn + cx1) * Cn;
        const float* p10 = xch + (cy1 * Wn + cx0) * Cn;
        const float* p11 = xch + (cy1 * Wn + cx1) * Cn;

        const float4 a00 = *(const float4*)p00, b00 = *(const float4*)(p00 + 4);
        const float4 a01 = *(const float4*)p01, b01 = *(const float4*)(p01 + 4);
        const float4 a10 = *(const float4*)p10, b10 = *(const float4*)(p10 + 4);
        const float4 a11 = *(const float4*)p11, b11 = *(const float4*)(p11 + 4);

        float s[8];
        s[0] = w00 * a00.x + w01 * a01.x + w10 * a10.x + w11 * a11.x;
        s[1] = w00 * a00.y + w01 * a01.y + w10 * a10.y + w11 * a11.y;
        s[2] = w00 * a00.z + w01 * a01.z + w10 * a10.z + w11 * a11.z;
        s[3] = w00 * a00.w + w01 * a01.w + w10 * a10.w + w11 * a11.w;
        s[4] = w00 * b00.x + w01 * b01.x + w10 * b10.x + w11 * b11.x;
        s[5] = w00 * b00.y + w01 * b01.y + w10 * b10.y + w11 * b11.y;
        s[6] = w00 * b00.z + w01 * b01.z + w10 * b10.z + w11 * b11.z;
        s[7] = w00 * b00.w + w01 * b01.w + w10 * b10.w + w11 * b11.w;

        const float* wk = wg + k * (CGn * CGn);   // wave-uniform [c][d]
        #pragma unroll
        for (int c = 0; c < 8; c++) {
            #pragma unroll
            for (int d = 0; d < CGn; d++)
                acc[d] += s[c] * wk[c * CGn + d];
        }
    }

    if (chunk == 1) {
        #pragma unroll
        for (int d = 0; d < CGn; d++) red[pl][d] = acc[d];
    }
    __syncthreads();
    if (chunk == 0) {
        float* op = out + (b * Cn + g * CGn) * HWn + pos;
        #pragma unroll
        for (int d = 0; d < CGn; d++) op[d * HWn] = acc[d] + red[pl][d];
    }
}

// ---------------------------------------------------------------------------
extern "C" void kernel_launch(void* const* d_in, const int* in_sizes, int n_in,
                              void* d_out, int out_size, void* d_ws, size_t ws_size,
                              hipStream_t stream) {
    const float* x     = (const float*)d_in[0];
    const float* w_off = (const float*)d_in[1];
    const float* b_off = (const float*)d_in[2];
    const float* w_def = (const float*)d_in[3];
    float* out = (float*)d_out;
    float* ws  = (float*)d_ws;

    const int n_prep = Cn * NOFF * KKn + Gn * KKn * CGn * CGn;  // 19584
    prep_kernel<<<(n_prep + 255) / 256, 256, 0, stream>>>(w_off, w_def, ws);

    transpose_x<<<Bn * (HWn / 64), 256, 0, stream>>>(x, ws + XT_BASE);

    offset_conv_v3<<<Bn * (HWn / OCB), 512, 0, stream>>>(x, ws, b_off, ws + OFF_BASE);

    deform_v4<<<Bn * Gn * (HWn / 128), 256, 0, stream>>>(ws, out);
}

// Round 5
// 86.216 us; speedup vs baseline: 3.0484x; 1.1858x over previous
//
#include <hip/hip_runtime.h>

// Problem constants
#define Bn   4
#define Cn   64
#define Hn   96
#define Wn   96
#define Gn   4
#define CGn  16      // Cn / Gn
#define KKn  9
#define NOFF 18      // 2*K*K offset channels
#define HWn  (Hn*Wn) // 9216

// ws layout (floats)
#define OFF_BASE  0                            // B*HW*18 pos-major offsets (663552)
#define WT_BASE   (Bn*HWn*NOFF)                // wT[ci][o][k]  (10368)
#define WDT_BASE  (WT_BASE + Cn*NOFF*KKn)      // wd2[g][k][c][d] (9216)
#define XT_BASE   (WDT_BASE + Gn*KKn*CGn*CGn)  // xT[b][pos][c] NHWC (2359296)

// ---------------------------------------------------------------------------
// Kernel 0 (fused): blocks [0,576) transpose x NCHW->NHWC; blocks >=576
// reorder the two weight tensors.
// ---------------------------------------------------------------------------
#define NTRB (Bn * (HWn / 64))   // 576 transpose blocks
__global__ __launch_bounds__(256) void prep_all(
    const float* __restrict__ x, const float* __restrict__ w_off,
    const float* __restrict__ w_def, float* __restrict__ ws)
{
    __shared__ float t[64][65];
    if (blockIdx.x < NTRB) {
        const int nb = HWn / 64;               // 144
        const int b  = blockIdx.x / nb;
        const int p0 = (blockIdx.x % nb) * 64;
        float* xT = ws + XT_BASE;
        for (int i = threadIdx.x; i < 64 * 64; i += 256) {
            const int c = i >> 6, l = i & 63;
            t[c][l] = x[(b * Cn + c) * HWn + p0 + l];
        }
        __syncthreads();
        for (int i = threadIdx.x; i < 64 * 64; i += 256) {
            const int l = i >> 6, c = i & 63;
            xT[(b * HWn + p0 + l) * Cn + c] = t[c][l];
        }
        return;
    }
    const int i = (blockIdx.x - NTRB) * 256 + threadIdx.x;
    const int NT = Cn * NOFF * KKn;        // 10368
    const int ND = Gn * KKn * CGn * CGn;   // 9216
    if (i < NT) {
        const int ci = i / (NOFF * KKn);
        const int r  = i % (NOFF * KKn);
        const int o  = r / KKn, k = r % KKn;
        ws[WT_BASE + i] = w_off[(o * Cn + ci) * KKn + k];
    } else if (i < NT + ND) {
        const int j = i - NT;
        const int d = j % CGn;
        const int c = (j / CGn) % CGn;
        const int k = (j / (CGn * CGn)) % KKn;
        const int g = j / (KKn * CGn * CGn);
        ws[WDT_BASE + j] = w_def[((g * CGn + d) * CGn + c) * KKn + k];
    }
}

// ---------------------------------------------------------------------------
// Kernel 1: offset conv (64 -> 18, 3x3, pad 1), ci-split across 8 waves.
// XCD-swizzled so each XCD works on one batch image (2.4 MB -> L2-resident).
// Writes offsets POS-MAJOR: offs[(b*HW+pos)*18 + o].
// ---------------------------------------------------------------------------
#define OCB 64
__global__ __launch_bounds__(512) void offset_conv_v3(
    const float* __restrict__ x, const float* __restrict__ ws,
    const float* __restrict__ bias, float* __restrict__ offs)
{
    __shared__ float red[8][OCB][NOFF + 1];
    const float* __restrict__ wT = ws + WT_BASE;

    // grid = 576 = 8 * 72: XCD k takes contiguous work [k*72, (k+1)*72)
    const int bid  = (blockIdx.x & 7) * 72 + (blockIdx.x >> 3);
    const int wave = threadIdx.x >> 6;
    const int lane = threadIdx.x & 63;
    const int nb   = HWn / OCB;            // 144
    const int b    = bid / nb;
    const int pbase= (bid % nb) * OCB;
    const int pos  = pbase + lane;
    const int ho = pos / Wn, wo = pos % Wn;

    float acc[NOFF];
    #pragma unroll
    for (int o = 0; o < NOFF; o++) acc[o] = 0.f;

    const float* xb = x + b * Cn * HWn;
    const int ci0 = __builtin_amdgcn_readfirstlane(wave * 8);

    for (int ci = ci0; ci < ci0 + 8; ci++) {
        const float* xc = xb + ci * HWn;
        float xv[KKn];
        #pragma unroll
        for (int ki = 0; ki < 3; ki++) {
            const int y = ho - 1 + ki;
            const bool vy = (y >= 0) && (y < Hn);
            const float* xr = xc + y * Wn;
            #pragma unroll
            for (int kj = 0; kj < 3; kj++) {
                const int xx = wo - 1 + kj;
                const bool v = vy && (xx >= 0) && (xx < Wn);
                xv[ki * 3 + kj] = v ? xr[xx] : 0.f;
            }
        }
        const float* wp = wT + ci * (NOFF * KKn);   // wave-uniform
        #pragma unroll
        for (int o = 0; o < NOFF; o++) {
            #pragma unroll
            for (int k = 0; k < KKn; k++)
                acc[o] += xv[k] * wp[o * KKn + k];
        }
    }

    #pragma unroll
    for (int o = 0; o < NOFF; o++) red[wave][lane][o] = acc[o];
    __syncthreads();

    for (int idx = threadIdx.x; idx < NOFF * OCB; idx += 512) {
        const int o = idx % NOFF;
        const int p = idx / NOFF;
        float s = bias[o];
        #pragma unroll
        for (int w2 = 0; w2 < 8; w2++) s += red[w2][p][o];
        offs[(b * HWn + pbase + p) * NOFF + o] = s;
    }
}

// ---------------------------------------------------------------------------
// Kernel 2: deformable conv from NHWC x. Block 256 = 128 pos x 2 c-chunks.
// 2-tap software pipeline (prefetch tap k+1 corners while FMA-ing tap k),
// 128-VGPR budget (4 waves/SIMD), XCD swizzle (2 bg per XCD, ~1.2MB in L2).
// ---------------------------------------------------------------------------
struct Tap {
    float4 v0, v1, v2, v3, v4, v5, v6, v7;  // 4 corners x 8 channels
    float  w0, w1, w2, w3;                  // bilinear corner weights
};

#define LOAD_TAP(K, T)                                                    \
  {                                                                       \
    const int ki = (K) / 3, kj = (K) % 3;                                 \
    const float ysf = (float)(ho - 1 + ki) + o2[K].x;                     \
    const float xsf = (float)(wo - 1 + kj) + o2[K].y;                     \
    const float y0f = floorf(ysf), x0f = floorf(xsf);                     \
    const int   y0  = (int)y0f,    x0  = (int)x0f;                        \
    const float wy1 = ysf - y0f, wx1 = xsf - x0f;                         \
    const float wy0 = 1.f - wy1, wx0 = 1.f - wx1;                         \
    const bool vy0 = (y0 >= 0)  && (y0 < Hn);                             \
    const bool vy1 = (y0 >= -1) && (y0 < Hn - 1);                         \
    const bool vx0 = (x0 >= 0)  && (x0 < Wn);                             \
    const bool vx1 = (x0 >= -1) && (x0 < Wn - 1);                         \
    const int cy0 = min(max(y0,     0), Hn - 1);                          \
    const int cy1 = min(max(y0 + 1, 0), Hn - 1);                          \
    const int cx0 = min(max(x0,     0), Wn - 1);                          \
    const int cx1 = min(max(x0 + 1, 0), Wn - 1);                          \
    (T).w0 = wy0 * wx0 * ((vy0 && vx0) ? 1.f : 0.f);                      \
    (T).w1 = wy0 * wx1 * ((vy0 && vx1) ? 1.f : 0.f);                      \
    (T).w2 = wy1 * wx0 * ((vy1 && vx0) ? 1.f : 0.f);                      \
    (T).w3 = wy1 * wx1 * ((vy1 && vx1) ? 1.f : 0.f);                      \
    const float* p00 = xch + (cy0 * Wn + cx0) * Cn;                       \
    const float* p01 = xch + (cy0 * Wn + cx1) * Cn;                       \
    const float* p10 = xch + (cy1 * Wn + cx0) * Cn;                       \
    const float* p11 = xch + (cy1 * Wn + cx1) * Cn;                       \
    (T).v0 = *(const float4*)p00; (T).v1 = *(const float4*)(p00 + 4);     \
    (T).v2 = *(const float4*)p01; (T).v3 = *(const float4*)(p01 + 4);     \
    (T).v4 = *(const float4*)p10; (T).v5 = *(const float4*)(p10 + 4);     \
    (T).v6 = *(const float4*)p11; (T).v7 = *(const float4*)(p11 + 4);     \
  }

__global__ __launch_bounds__(256, 4) void deform_v5(
    const float* __restrict__ ws, float* __restrict__ out)
{
    __shared__ float red[128][CGn + 1];
    const float* __restrict__ off2 = ws + OFF_BASE;
    const float* __restrict__ wd   = ws + WDT_BASE;
    const float* __restrict__ xT   = ws + XT_BASE;

    // grid = 1152 = 8 * 144: XCD k takes work [k*144, (k+1)*144) = bg {2k,2k+1}
    const int bid = (blockIdx.x & 7) * 144 + (blockIdx.x >> 3);
    const int nb = HWn / 128;              // 72
    const int bg = bid / nb;
    const int g  = bg & (Gn - 1);
    const int b  = bg >> 2;
    const int chunk = threadIdx.x >> 7;    // wave-uniform (0 or 1)
    const int pl    = threadIdx.x & 127;
    const int pos   = (bid % nb) * 128 + pl;
    const int ho = pos / Wn, wo = pos % Wn;

    // hoist all 9 (dy,dx) pairs
    const float2* op2 = (const float2*)(off2 + (b * HWn + pos) * NOFF);
    float2 o2[KKn];
    #pragma unroll
    for (int k = 0; k < KKn; k++) o2[k] = op2[k];

    const int c0 = __builtin_amdgcn_readfirstlane(chunk * 8);
    const float* xch = xT + (b * HWn) * Cn + g * CGn + c0;
    const float* wg  = wd + g * (KKn * CGn * CGn) + c0 * CGn;

    float acc[CGn];
    #pragma unroll
    for (int d = 0; d < CGn; d++) acc[d] = 0.f;

    Tap cur, nxt;
    LOAD_TAP(0, cur);

    #pragma unroll
    for (int k = 0; k < KKn; k++) {
        if (k + 1 < KKn) LOAD_TAP(k + 1, nxt);

        float s[8];
        s[0] = cur.w0 * cur.v0.x + cur.w1 * cur.v2.x + cur.w2 * cur.v4.x + cur.w3 * cur.v6.x;
        s[1] = cur.w0 * cur.v0.y + cur.w1 * cur.v2.y + cur.w2 * cur.v4.y + cur.w3 * cur.v6.y;
        s[2] = cur.w0 * cur.v0.z + cur.w1 * cur.v2.z + cur.w2 * cur.v4.z + cur.w3 * cur.v6.z;
        s[3] = cur.w0 * cur.v0.w + cur.w1 * cur.v2.w + cur.w2 * cur.v4.w + cur.w3 * cur.v6.w;
        s[4] = cur.w0 * cur.v1.x + cur.w1 * cur.v3.x + cur.w2 * cur.v5.x + cur.w3 * cur.v7.x;
        s[5] = cur.w0 * cur.v1.y + cur.w1 * cur.v3.y + cur.w2 * cur.v5.y + cur.w3 * cur.v7.y;
        s[6] = cur.w0 * cur.v1.z + cur.w1 * cur.v3.z + cur.w2 * cur.v5.z + cur.w3 * cur.v7.z;
        s[7] = cur.w0 * cur.v1.w + cur.w1 * cur.v3.w + cur.w2 * cur.v5.w + cur.w3 * cur.v7.w;

        const float* wk = wg + k * (CGn * CGn);   // wave-uniform [c][d]
        #pragma unroll
        for (int c = 0; c < 8; c++) {
            #pragma unroll
            for (int d = 0; d < CGn; d++)
                acc[d] += s[c] * wk[c * CGn + d];
        }
        cur = nxt;
    }

    if (chunk == 1) {
        #pragma unroll
        for (int d = 0; d < CGn; d++) red[pl][d] = acc[d];
    }
    __syncthreads();
    if (chunk == 0) {
        float* op = out + (b * Cn + g * CGn) * HWn + pos;
        #pragma unroll
        for (int d = 0; d < CGn; d++) op[d * HWn] = acc[d] + red[pl][d];
    }
}

// ---------------------------------------------------------------------------
extern "C" void kernel_launch(void* const* d_in, const int* in_sizes, int n_in,
                              void* d_out, int out_size, void* d_ws, size_t ws_size,
                              hipStream_t stream) {
    const float* x     = (const float*)d_in[0];
    const float* w_off = (const float*)d_in[1];
    const float* b_off = (const float*)d_in[2];
    const float* w_def = (const float*)d_in[3];
    float* out = (float*)d_out;
    float* ws  = (float*)d_ws;

    const int n_prep = Cn * NOFF * KKn + Gn * KKn * CGn * CGn;  // 19584
    const int nblk = NTRB + (n_prep + 255) / 256;               // 576 + 77

    prep_all<<<nblk, 256, 0, stream>>>(x, w_off, w_def, ws);

    offset_conv_v3<<<Bn * (HWn / OCB), 512, 0, stream>>>(x, ws, b_off, ws + OFF_BASE);

    deform_v5<<<Bn * Gn * (HWn / 128), 256, 0, stream>>>(ws, out);
}